// Round 10
// baseline (157.482 us; speedup 1.0000x reference)
//
#include <hip/hip_runtime.h>
#include <math.h>

// Problem constants (fixed by setup_inputs)
#define W_ 192
#define H_ 192
#define D_ 160
#define B_ 2
#define HW_ (H_ * W_)

#define TX 32             // output tile x
#define TY 8              // output tile y
#define HY 12             // halo rows (TY + 4)
#define RAWP 41           // raw row stride, 40 data cols + odd stride (<=2-way banks)
#define RSP  33           // rowsum row stride, 32 data cols + odd stride (<=2-way banks)
#define BUFR (HY * RAWP)  // 492 floats between raw double-buffers
#define BUFS (HY * RSP)   // 396 floats between rs double-buffers
#define CHUNK 20          // z-planes of output per block
#define PLANES (CHUNK + 4)
#define GX 6              // 192/32
#define GY 24             // 192/8
#define GZ 16             // 8 z-chunks * 2 batches
#define NBLK (GX * GY * GZ)   // 2304
#define NTOT 11796480.0f      // 2*1*160*192*192

__global__ __launch_bounds__(256) void lncc_main(const float* __restrict__ src,
                                                 const float* __restrict__ tgt,
                                                 float* __restrict__ partial) {
    // SoA float LDS, double-buffered; 23728 B -> 6 blocks/CU resident.
    __shared__ float rawS[2][HY][RAWP];
    __shared__ float rawT[2][HY][RAWP];
    __shared__ float rsS [2][HY][RSP];
    __shared__ float rsT [2][HY][RSP];
    __shared__ float rsS2[2][HY][RSP];
    __shared__ float rsT2[2][HY][RSP];
    __shared__ float rsST[2][HY][RSP];
    __shared__ float wsum[4];

    const int tid = threadIdx.x;
    const int bz  = blockIdx.z;
    const int b   = bz >> 3;                 // 8 chunks per batch
    const int z0  = (bz & 7) * CHUNK;
    const int bx0 = blockIdx.x * TX - 4;     // raw col 0 <-> gx = bx0 (16B-aligned)
    const int by0 = blockIdx.y * TY - 2;

    // ---- staging decode: tid<120 loads one aligned float4 per array ----
    const int  sr  = tid / 10;               // row 0..11 (valid when sW)
    const int  sc4 = tid - sr * 10;          // float4 col 0..9
    const int  sc  = sc4 * 4;                // word col 0,4,..,36
    const int  sgx = bx0 + sc;               // multiple of 4 -> float4 aligned
    const int  sgy = by0 + sr;
    const bool sW  = (tid < 120);
    const bool sOk = sW && ((unsigned)sgx < (unsigned)W_) && ((unsigned)sgy < (unsigned)H_);
    const size_t sOff = (size_t)sgy * W_ + (size_t)sgx;   // valid only when sOk
    const int  srP = (sr < HY - 1) ? sr : (HY - 1);       // clamped for base-ptr calc

    // ---- phase1 decode: 16 x-pairs x 12 rows = 192 threads, one rep ----
    const int  p0y = tid >> 4;               // row (only tid<192 active)
    const int  xp  = tid & 15;
    const bool pAct = (tid < 192);
    const int  rc  = 2 * xp + 2;             // raw read col base (window of out 2*xp)
    const int  wc  = 2 * xp;                 // rs write col base
    const int  p0yP = (p0y < HY - 1) ? p0y : (HY - 1);    // clamped for base-ptr calc

    // ---- phase2 decode: thread owns output row y0, column tx ----
    const int tx = tid & 31;                 // 0..31
    const int y0 = tid >> 5;                 // 0..7

    // Hoisted LDS base pointers; double-buffer parity goes into the ds imm
    // offset (BUF*BUFR / BUF*BUFS words, compile-time in the unrolled loop).
    const float* prS = &rawS[0][p0yP][rc];   // phase1 raw reads
    const float* prT = &rawT[0][p0yP][rc];
    float* pwS = &rsS [0][p0yP][wc];         // phase1 rs writes
    float* pwT = &rsT [0][p0yP][wc];
    float* pwA = &rsS2[0][p0yP][wc];
    float* pwB = &rsT2[0][p0yP][wc];
    float* pwC = &rsST[0][p0yP][wc];
    const float* pqS = &rsS [0][y0][tx];     // phase2 rs reads
    const float* pqT = &rsT [0][y0][tx];
    const float* pqA = &rsS2[0][y0][tx];
    const float* pqB = &rsT2[0][y0][tx];
    const float* pqC = &rsST[0][y0][tx];
    float* psS = &rawS[0][srP][sc];          // staging raw writes
    float* psT = &rawT[0][srP][sc];

    // z-ring: NAMED scalars only (arrays -> scratch: round-4 disaster, rule #20).
    float q0s=0,q0t=0,q0a=0,q0b=0,q0c=0;
    float q1s=0,q1t=0,q1a=0,q1b=0,q1c=0;
    float q2s=0,q2t=0,q2a=0,q2b=0,q2c=0;
    float q3s=0,q3t=0,q3a=0,q3b=0,q3c=0;
    float q4s=0,q4t=0,q4a=0,q4b=0,q4c=0;
    float zS=0,zT=0,zA=0,zB=0,zC=0;
    float lsum = 0.0f;

    // phase2 for plane J, rowsums in buffer BUF (literal): y-sum + z-window + LNCC
    #define PH2(BUF, J) do {                                                      \
        float yS = pqS[(BUF)*BUFS] + pqS[(BUF)*BUFS+RSP] + pqS[(BUF)*BUFS+2*RSP]  \
                 + pqS[(BUF)*BUFS+3*RSP] + pqS[(BUF)*BUFS+4*RSP];                 \
        float yT = pqT[(BUF)*BUFS] + pqT[(BUF)*BUFS+RSP] + pqT[(BUF)*BUFS+2*RSP]  \
                 + pqT[(BUF)*BUFS+3*RSP] + pqT[(BUF)*BUFS+4*RSP];                 \
        float yA = pqA[(BUF)*BUFS] + pqA[(BUF)*BUFS+RSP] + pqA[(BUF)*BUFS+2*RSP]  \
                 + pqA[(BUF)*BUFS+3*RSP] + pqA[(BUF)*BUFS+4*RSP];                 \
        float yB = pqB[(BUF)*BUFS] + pqB[(BUF)*BUFS+RSP] + pqB[(BUF)*BUFS+2*RSP]  \
                 + pqB[(BUF)*BUFS+3*RSP] + pqB[(BUF)*BUFS+4*RSP];                 \
        float yC = pqC[(BUF)*BUFS] + pqC[(BUF)*BUFS+RSP] + pqC[(BUF)*BUFS+2*RSP]  \
                 + pqC[(BUF)*BUFS+3*RSP] + pqC[(BUF)*BUFS+4*RSP];                 \
        zS += yS - q0s;  zT += yT - q0t;  zA += yA - q0a;                         \
        zB += yB - q0b;  zC += yC - q0c;                                          \
        q0s=q1s; q0t=q1t; q0a=q1a; q0b=q1b; q0c=q1c;                              \
        q1s=q2s; q1t=q2t; q1a=q2a; q1b=q2b; q1c=q2c;                              \
        q2s=q3s; q2t=q3t; q2a=q3a; q2b=q3b; q2c=q3c;                              \
        q3s=q4s; q3t=q4t; q3a=q4a; q3b=q4b; q3c=q4c;                              \
        q4s=yS;  q4t=yT;  q4a=yA;  q4b=yB;  q4c=yC;                               \
        if ((J) >= 4) {                                                           \
            const float inv = 1.0f / 125.0f;                                      \
            float ms = zS * inv, mt = zT * inv;                                   \
            float vs = fmaf(-ms, ms, zA * inv);                                   \
            float vt = fmaf(-mt, mt, zB * inv);                                   \
            float cr = fmaf(-ms, mt, zC * inv);                                   \
            float den = fmaf(vs, vt, 1e-5f);                                      \
            lsum = fmaf(cr * cr, __builtin_amdgcn_rcpf(den), lsum);               \
        }                                                                         \
    } while (0)

    // phase1 for buffer BUF (literal): sliding x-window, 6 raw words -> 2 rowsums
    #define ROWSUM(BUF) do { if (pAct) {                                          \
        float v0=prS[(BUF)*BUFR+0], v1=prS[(BUF)*BUFR+1], v2=prS[(BUF)*BUFR+2],   \
              v3=prS[(BUF)*BUFR+3], v4=prS[(BUF)*BUFR+4], v5=prS[(BUF)*BUFR+5];   \
        float u0=prT[(BUF)*BUFR+0], u1=prT[(BUF)*BUFR+1], u2=prT[(BUF)*BUFR+2],   \
              u3=prT[(BUF)*BUFR+3], u4=prT[(BUF)*BUFR+4], u5=prT[(BUF)*BUFR+5];   \
        float m  = v1 + v2 + v3 + v4;                                             \
        float n  = u1 + u2 + u3 + u4;                                             \
        float qS = fmaf(v1,v1, fmaf(v2,v2, fmaf(v3,v3, v4*v4)));                  \
        float qT = fmaf(u1,u1, fmaf(u2,u2, fmaf(u3,u3, u4*u4)));                  \
        float qX = fmaf(v1,u1, fmaf(v2,u2, fmaf(v3,u3, v4*u4)));                  \
        pwS[(BUF)*BUFS+0] = v0 + m;            pwS[(BUF)*BUFS+1] = m + v5;        \
        pwT[(BUF)*BUFS+0] = u0 + n;            pwT[(BUF)*BUFS+1] = n + u5;        \
        pwA[(BUF)*BUFS+0] = fmaf(v0,v0,qS);    pwA[(BUF)*BUFS+1] = fmaf(v5,v5,qS);\
        pwB[(BUF)*BUFS+0] = fmaf(u0,u0,qT);    pwB[(BUF)*BUFS+1] = fmaf(u5,u5,qT);\
        pwC[(BUF)*BUFS+0] = fmaf(v0,u0,qX);    pwC[(BUF)*BUFS+1] = fmaf(v5,u5,qX);\
    } } while (0)

    // One plane iteration. BUF = I&1 (literal), WBUF = BUF^1 (literal).
    #define ITER(I, BUF, WBUF) do {                                               \
        __syncthreads();   /* the ONLY barrier per plane */                       \
        float4 vS = make_float4(0,0,0,0), vT = make_float4(0,0,0,0);              \
        const int  zpn = z0 - 1 + (I);                                            \
        const bool haveNext = (I) + 1 < PLANES;                                   \
        if (haveNext && zpn >= 0 && zpn < D_ && sOk) {                            \
            const size_t base = (size_t)(b * D_ + zpn) * (size_t)HW_;             \
            vS = *(const float4*)(src + base + sOff);                             \
            vT = *(const float4*)(tgt + base + sOff);                             \
        }                                                                         \
        if ((I) >= 1) PH2((BUF) ^ 1, (I) - 1);                                    \
        ROWSUM(BUF);                                                              \
        if (haveNext && sW) {                                                     \
            psS[(WBUF)*BUFR+0]=vS.x; psS[(WBUF)*BUFR+1]=vS.y;                     \
            psS[(WBUF)*BUFR+2]=vS.z; psS[(WBUF)*BUFR+3]=vS.w;                     \
            psT[(WBUF)*BUFR+0]=vT.x; psT[(WBUF)*BUFR+1]=vT.y;                     \
            psT[(WBUF)*BUFR+2]=vT.z; psT[(WBUF)*BUFR+3]=vT.w;                     \
        }                                                                         \
    } while (0)

    // ---- prologue: stage plane 0 (z = z0-2) into raw buffer 0 ----
    {
        float4 vS = make_float4(0,0,0,0), vT = make_float4(0,0,0,0);
        const int zp = z0 - 2;
        if (zp >= 0 && sOk) {
            const size_t base = (size_t)(b * D_ + zp) * (size_t)HW_;
            vS = *(const float4*)(src + base + sOff);
            vT = *(const float4*)(tgt + base + sOff);
        }
        if (sW) {
            psS[0]=vS.x; psS[1]=vS.y; psS[2]=vS.z; psS[3]=vS.w;
            psT[0]=vT.x; psT[1]=vT.y; psT[2]=vT.z; psT[3]=vT.w;
        }
    }

    // ---- main pipeline: peel i=0, 2-unrolled middle, tail i=23 ----
    ITER(0, 0, 1);
    for (int ip = 1; ip < PLANES - 1; ip += 2) {   // ip = 1,3,...,21 -> i=1..22
        ITER(ip,     1, 0);
        ITER(ip + 1, 0, 1);
    }
    ITER(PLANES - 1, 1, 0);                        // i = 23 (no load, no store)

    __syncthreads();
    PH2(1, PLANES - 1);                            // drain: j=23, buffer 1

    #undef ITER
    #undef ROWSUM
    #undef PH2

    // block reduction -> per-block partial (no atomics, no zero-kernel)
    #pragma unroll
    for (int off = 32; off > 0; off >>= 1)
        lsum += __shfl_down(lsum, off, 64);
    if ((tid & 63) == 0) wsum[tid >> 6] = lsum;
    __syncthreads();
    if (tid == 0) {
        const int bid = (blockIdx.z * GY + blockIdx.y) * GX + blockIdx.x;
        partial[bid] = wsum[0] + wsum[1] + wsum[2] + wsum[3];
    }
}

__global__ __launch_bounds__(256) void lncc_finalize(const float* __restrict__ partial,
                                                     float* __restrict__ out) {
    __shared__ float ws[4];
    const int t = threadIdx.x;
    float s = 0.0f;
    for (int i = t; i < NBLK; i += 256) s += partial[i];
    #pragma unroll
    for (int off = 32; off > 0; off >>= 1) s += __shfl_down(s, off, 64);
    if ((t & 63) == 0) ws[t >> 6] = s;
    __syncthreads();
    if (t == 0) {
        float tot = ws[0] + ws[1] + ws[2] + ws[3];
        float loss = 1.0f - tot * (1.0f / NTOT);
        if (isnan(loss) || isinf(loss)) loss = 1.0f;
        *out = loss;
    }
}

extern "C" void kernel_launch(void* const* d_in, const int* in_sizes, int n_in,
                              void* d_out, int out_size, void* d_ws, size_t ws_size,
                              hipStream_t stream) {
    const float* src = (const float*)d_in[0];
    const float* tgt = (const float*)d_in[1];
    float* out = (float*)d_out;
    float* partial = (float*)d_ws;   // NBLK floats of scratch

    dim3 grid(GX, GY, GZ);           // 6 x 24 x 16 = 2304 blocks
    dim3 block(256, 1, 1);
    lncc_main<<<grid, block, 0, stream>>>(src, tgt, partial);
    lncc_finalize<<<dim3(1), dim3(256), 0, stream>>>(partial, out);
}